// Round 7
// baseline (545.353 us; speedup 1.0000x reference)
//
#include <hip/hip_runtime.h>
#include <math.h>

#define N_ANGLES 180
#define P 724
#define PSTRIDE 520            // padded row stride (floats)
#define PROWS 516              // padded rows
#define IMGFLOATS (PROWS * PSTRIDE)   // 268320
#define TJ 64                  // tile width  (j, lanes)
#define TI 36                  // tile height (i, rows)
#define TILES_J 12             // ceil(724/64)
#define TILES_I 21             // ceil(724/36)
#define LDS_ROWS 77            // >= max box height (sqrt(63^2+35^2)+4 = 76.1)
#define LDS_STRIDE 130         // even (float2 align); 130 mod 32 = 2 bank shift/row

// ---------------- prep: trig + padded image + padded transpose + sino zero ----
__global__ __launch_bounds__(256) void prep_pad(const float* __restrict__ in,
                                                float* __restrict__ img0,
                                                float* __restrict__ imgT,
                                                float2* __restrict__ sc,
                                                float* __restrict__ sino) {
    const int bid = blockIdx.y * 17 + blockIdx.x;
    if (bid == 0) {
        int t = threadIdx.x;
        if (t < N_ANGLES) {
            float deg = (float)t * (180.0f / 179.0f);
            float ang = deg * (float)(M_PI / 180.0);
            sc[t] = make_float2(cosf(ang), sinf(ang));
        }
    }
    // zero sinogram (atomics accumulate into it)
    if (bid < 510) {
        int idx = bid * 256 + threadIdx.x;
        if (idx < N_ANGLES * P) sino[idx] = 0.0f;
    }
    const int xcol = blockIdx.x * 32 + (threadIdx.x & 31);
    const int yrow = blockIdx.y * 8 + (threadIdx.x >> 5);
    if (xcol < PSTRIDE && yrow < PROWS) {
        const unsigned xi = (unsigned)(xcol - 1), yi = (unsigned)(yrow - 1);
        const bool inb = (xi < 512u) && (yi < 512u);
        img0[yrow * PSTRIDE + xcol] = inb ? in[yi * 512u + xi] : 0.0f;
        imgT[yrow * PSTRIDE + xcol] = inb ? in[xi * 512u + yi] : 0.0f;
    }
}

// ---------------- main kernel: LDS-staged tile gather ----------------
// Block = (angle, 64j x 36i output tile). Stage the tile's image-space
// bounding box (<=77x78) into LDS once (coalesced), gather bilinear taps
// from LDS (no L1 transaction amplification). Stores: full-wave contiguous
// NT dwords. Sino: per-row partial sums via atomicAdd (sino pre-zeroed).
__global__ __launch_bounds__(256) void radon_tiled(
    const float2* __restrict__ sc,
    const float* __restrict__ img0,
    const float* __restrict__ imgT,
    float* __restrict__ sino,
    float* __restrict__ rot)
{
    __shared__ float lds[LDS_ROWS * LDS_STRIDE];

    const int a  = blockIdx.y;
    const int bt = blockIdx.x;
    const int jt = bt % TILES_J;
    const int it = bt / TILES_J;
    const int j0 = jt * TJ;
    const int i0 = it * TI;
    const int tid = threadIdx.x;
    const int w = tid >> 6, l = tid & 63;

    const float2 cs = sc[a];
    const float c = cs.x, s = cs.y;
    // padded coords: px = c*j - s*i + Ax, py = s*j + c*i + Ay; live iff in (0,513)
    const float Ax = 256.5f - 361.5f * (c - s);
    const float Ay = 256.5f - 361.5f * (s + c);

    // axis swap: fast (LDS-contiguous) axis gets the larger per-j step
    const bool useT = fabsf(s) > fabsf(c);
    const float* __restrict__ bimg = useT ? imgT : img0;
    const float FcJ = useT ? s : c;      // fast coord coeffs
    const float FcI = useT ? c : -s;
    const float F0  = useT ? Ay : Ax;
    const float ScJ = useT ? c : s;      // slow coord coeffs
    const float ScI = useT ? -s : c;
    const float S0  = useT ? Ax : Ay;

    // tile bounding box from the 4 corners (block-uniform)
    const float jA = (float)j0, jB = (float)min(j0 + TJ - 1, P - 1);
    const float iA = (float)i0, iB = (float)min(i0 + TI - 1, P - 1);
    const float FjA = fmaf(FcJ, jA, F0), FjB = fmaf(FcJ, jB, F0);
    const float SjA = fmaf(ScJ, jA, S0), SjB = fmaf(ScJ, jB, S0);
    const float Fc[4] = { fmaf(FcI, iA, FjA), fmaf(FcI, iB, FjA),
                          fmaf(FcI, iA, FjB), fmaf(FcI, iB, FjB) };
    const float Sc[4] = { fmaf(ScI, iA, SjA), fmaf(ScI, iB, SjA),
                          fmaf(ScI, iA, SjB), fmaf(ScI, iB, SjB) };
    const float minF = fminf(fminf(Fc[0], Fc[1]), fminf(Fc[2], Fc[3]));
    const float maxF = fmaxf(fmaxf(Fc[0], Fc[1]), fmaxf(Fc[2], Fc[3]));
    const float minS = fminf(fminf(Sc[0], Sc[1]), fminf(Sc[2], Sc[3]));
    const float maxS = fmaxf(fmaxf(Sc[0], Sc[1]), fmaxf(Sc[2], Sc[3]));

    const int f0 = max(0, (int)floorf(minF) - 1) & ~1;   // even for float2 staging
    const int f1 = min(519, (int)floorf(maxF) + 2);
    const int s0 = max(0, (int)floorf(minS) - 1);
    const int s1 = min(515, (int)floorf(maxS) + 2);

    const int jlane = j0 + l;
    const bool jvalid = jlane < P;

    if (f1 < f0 || s1 < s0) {
        // dead tile: zero stores only (sino contribution is 0)
        for (int il = w; il < TI; il += 4) {
            const int i = i0 + il;
            if (i >= P) break;
            if (jvalid)
                __builtin_nontemporal_store(0.0f, rot + ((size_t)a * P + i) * P + jlane);
        }
        return;
    }

    const int BH = min(s1 - s0 + 1, LDS_ROWS);
    const int BW = f1 - f0 + 1;                          // <= 78

    // stage box rows: coalesced float2 loads, 128 cols per row
    {
        const float* src0 = bimg + (size_t)s0 * PSTRIDE + f0 + 2 * l;
        for (int r = w; r < BH; r += 4) {
            const float2 v = *(const float2*)(src0 + (size_t)r * PSTRIDE);
            *(float2*)&lds[r * LDS_STRIDE + 2 * l] = v;
        }
    }
    __syncthreads();

    const float jlf = (float)jlane;
    const float Fj = fmaf(FcJ, jlf, F0);
    const float Sj = fmaf(ScJ, jlf, S0);
    const int lxm = max(BW - 2, 0);
    const int lym = max(BH - 2, 0);

    for (int il = w; il < TI; il += 4) {
        const int i = i0 + il;
        if (i >= P) break;
        const float fi = (float)i;
        const float F = fmaf(FcI, fi, Fj);
        const float S = fmaf(ScI, fi, Sj);
        const bool live = (F > 0.0f) && (F < 513.0f) &&
                          (S > 0.0f) && (S < 513.0f) && jvalid;
        const float Ff = floorf(F), Sf = floorf(S);
        const float wf1 = F - Ff, ws1 = S - Sf;
        const float wf0 = 1.0f - wf1, ws0 = 1.0f - ws1;
        const int lx = min(max((int)Ff - f0, 0), lxm);   // dead lanes clamped in-box
        const int ly = min(max((int)Sf - s0, 0), lym);
        const float* bp = &lds[ly * LDS_STRIDE + lx];
        const float v00 = bp[0],          v01 = bp[1];
        const float v10 = bp[LDS_STRIDE], v11 = bp[LDS_STRIDE + 1];
        float v = fmaf(ws1, fmaf(wf1, v11, wf0 * v10),
                       ws0 * fmaf(wf1, v01, wf0 * v00));
        v = live ? v : 0.0f;
        if (jvalid)
            __builtin_nontemporal_store(v, rot + ((size_t)a * P + i) * P + jlane);
        // row partial sum -> sino
        float rsum = v;
        for (int off = 32; off > 0; off >>= 1)
            rsum += __shfl_down(rsum, off, 64);
        if (l == 0) atomicAdd(&sino[a * P + i], rsum);
    }
}

// ---------------- fallback (no workspace): direct bounds-checked gather ------
__global__ __launch_bounds__(256) void radon_fallback(
    const float* __restrict__ x, float* __restrict__ sino, float* __restrict__ rot)
{
    const int a = blockIdx.y, i = blockIdx.x, tid = threadIdx.x;
    const float deg = (float)a * (180.0f / 179.0f);
    const float ang = deg * (float)(M_PI / 180.0);
    const float c = cosf(ang), s = sinf(ang);
    const float fi = (float)i - 361.5f;
    const float Kx = 255.5f - 361.5f * c - s * fi;
    const float Ky = 255.5f - 361.5f * s + c * fi;
    float* rrow = rot + (size_t)(a * P + i) * P;
    float lsum = 0.0f;
    for (int j = tid; j < P; j += 256) {
        const float jf = (float)j;
        const float ix = fmaf(jf, c, Kx), iy = fmaf(jf, s, Ky);
        const float x0f = floorf(ix), y0f = floorf(iy);
        const int x0 = (int)x0f, y0 = (int)y0f;
        const int x1 = x0 + 1, y1 = y0 + 1;
        float wx1 = ix - x0f, wy1 = iy - y0f;
        float wx0 = 1.0f - wx1, wy0 = 1.0f - wy1;
        wx0 = ((unsigned)x0 < 512u) ? wx0 : 0.0f;
        wx1 = ((unsigned)x1 < 512u) ? wx1 : 0.0f;
        wy0 = ((unsigned)y0 < 512u) ? wy0 : 0.0f;
        wy1 = ((unsigned)y1 < 512u) ? wy1 : 0.0f;
        const int xa = min(max(x0, 0), 511), xb = min(max(x1, 0), 511);
        const int ya = min(max(y0, 0), 511), yb = min(max(y1, 0), 511);
        const float v00 = x[(ya << 9) + xa], v01 = x[(ya << 9) + xb];
        const float v10 = x[(yb << 9) + xa], v11 = x[(yb << 9) + xb];
        const float val = fmaf(wy1, fmaf(wx1, v11, wx0 * v10),
                               wy0 * fmaf(wx1, v01, wx0 * v00));
        __builtin_nontemporal_store(val, &rrow[j]);
        lsum += val;
    }
    for (int off = 32; off > 0; off >>= 1) lsum += __shfl_down(lsum, off, 64);
    __shared__ float ws_red[4];
    if ((tid & 63) == 0) ws_red[tid >> 6] = lsum;
    __syncthreads();
    if (tid == 0) sino[a * P + i] = ws_red[0] + ws_red[1] + ws_red[2] + ws_red[3];
}

// ---------------- launch ----------------
extern "C" void kernel_launch(void* const* d_in, const int* in_sizes, int n_in,
                              void* d_out, int out_size, void* d_ws, size_t ws_size,
                              hipStream_t stream) {
    const float* x = (const float*)d_in[0];
    float* sino = (float*)d_out;                       // [180*724]
    float* rot  = sino + (size_t)N_ANGLES * P;         // [180*724*724]
    float* ws   = (float*)d_ws;

    // layout: trig(512) | img0(268320) | imgT(268320) | slop(128)
    const size_t need = (size_t)(512 + 2 * IMGFLOATS + 128) * sizeof(float);

    if (ws && ws_size >= need) {
        float* img0 = ws + 512;
        float* imgT = img0 + IMGFLOATS;
        prep_pad<<<dim3(17, 65), dim3(256), 0, stream>>>(x, img0, imgT, (float2*)ws, sino);
        radon_tiled<<<dim3(TILES_J * TILES_I, N_ANGLES), dim3(256), 0, stream>>>(
            (const float2*)ws, img0, imgT, sino, rot);
    } else {
        radon_fallback<<<dim3(P, N_ANGLES), dim3(256), 0, stream>>>(x, sino, rot);
    }
}

// Round 8
// 472.873 us; speedup vs baseline: 1.1533x; 1.1533x over previous
//
#include <hip/hip_runtime.h>
#include <math.h>

#define N_ANGLES 180
#define P 724
#define PSTRIDE 520            // padded row stride (floats)
#define PROWS 516              // padded rows
#define IMGFLOATS (PROWS * PSTRIDE)
#define TJ 64                  // tile width (j = lanes)
#define TI 36                  // tile height (i rows)
#define TILES_J 12             // ceil(724/64)
#define TILES_I 21             // ceil(724/36)
#define LDS_ROWS 77            // worst box: sqrt(63^2+35^2)=72.1 + margins
#define LDS_W 80               // staged cols (f0 4-aligned; span<=78.1)
#define LDS_STRIDE 84          // mult of 4 (float4); 84 mod 32 = 20 bank shift/row
#define STAGE_QUADS (LDS_ROWS * (LDS_W / 4))   // 77*20 = 1540

typedef float vfloat4 __attribute__((ext_vector_type(4)));

// ---------------- prep: trig + padded image + padded transpose + sino zero ----
__global__ __launch_bounds__(256) void prep_pad(const float* __restrict__ in,
                                                float* __restrict__ img0,
                                                float* __restrict__ imgT,
                                                float2* __restrict__ sc,
                                                float* __restrict__ sino) {
    const int bid = blockIdx.y * 17 + blockIdx.x;
    if (bid == 0) {
        int t = threadIdx.x;
        if (t < N_ANGLES) {
            float deg = (float)t * (180.0f / 179.0f);
            float ang = deg * (float)(M_PI / 180.0);
            sc[t] = make_float2(cosf(ang), sinf(ang));
        }
    }
    if (bid < 510) {                       // zero sinogram (atomics accumulate)
        int idx = bid * 256 + threadIdx.x;
        if (idx < N_ANGLES * P) sino[idx] = 0.0f;
    }
    const int xcol = blockIdx.x * 32 + (threadIdx.x & 31);
    const int yrow = blockIdx.y * 8 + (threadIdx.x >> 5);
    if (xcol < PSTRIDE && yrow < PROWS) {
        const unsigned xi = (unsigned)(xcol - 1), yi = (unsigned)(yrow - 1);
        const bool inb = (xi < 512u) && (yi < 512u);
        img0[yrow * PSTRIDE + xcol] = inb ? in[yi * 512u + xi] : 0.0f;
        imgT[yrow * PSTRIDE + xcol] = inb ? in[xi * 512u + yi] : 0.0f;
    }
}

// ---------------- main kernel: LDS-staged tile gather (fixed) ----------------
// Block = (angle, 64j x 36i tile). Live tiles stage a fixed 77x80 box (float4,
// 2.7 staged floats/px) into 25.9KB LDS (6 blocks/CU), then bilinear-gather
// from LDS. Dead tiles (box misses data) store zeros only. Stores: full-wave
// contiguous NT dwords. Sino: per-row wave reduce + atomicAdd (pre-zeroed).
__global__ __launch_bounds__(256) void radon_tiled(
    const float2* __restrict__ sc,
    const float* __restrict__ img0,
    const float* __restrict__ imgT,
    float* __restrict__ sino,
    float* __restrict__ rot)
{
    __shared__ float lds[LDS_ROWS * LDS_STRIDE];

    const int a  = blockIdx.y;
    const int bt = blockIdx.x;
    const int jt = bt % TILES_J;
    const int it = bt / TILES_J;
    const int j0 = jt * TJ;
    const int i0 = it * TI;
    const int tid = threadIdx.x;
    const int w = tid >> 6, l = tid & 63;

    const float2 cs = sc[a];
    const float c = cs.x, s = cs.y;
    // padded coords (+1 ring): F,S live iff in (0,513)
    const float Ax = 256.5f - 361.5f * (c - s);
    const float Ay = 256.5f - 361.5f * (s + c);

    // axis swap: fast (LDS-contiguous) axis has |FcJ| >= 0.707
    const bool useT = fabsf(s) > fabsf(c);
    const float* __restrict__ bimg = useT ? imgT : img0;
    const float FcJ = useT ? s : c;
    const float FcI = useT ? c : -s;
    const float F0  = useT ? Ay : Ax;
    const float ScJ = useT ? c : s;
    const float ScI = useT ? -s : c;
    const float S0  = useT ? Ax : Ay;

    // tile corner range (block-uniform)
    const float jA = (float)j0, jB = (float)min(j0 + TJ - 1, P - 1);
    const float iA = (float)i0, iB = (float)min(i0 + TI - 1, P - 1);
    const float FjA = fmaf(FcJ, jA, F0), FjB = fmaf(FcJ, jB, F0);
    const float SjA = fmaf(ScJ, jA, S0), SjB = fmaf(ScJ, jB, S0);
    const float Fc0 = fmaf(FcI, iA, FjA), Fc1 = fmaf(FcI, iB, FjA);
    const float Fc2 = fmaf(FcI, iA, FjB), Fc3 = fmaf(FcI, iB, FjB);
    const float Sc0 = fmaf(ScI, iA, SjA), Sc1 = fmaf(ScI, iB, SjA);
    const float Sc2 = fmaf(ScI, iA, SjB), Sc3 = fmaf(ScI, iB, SjB);
    const float minF = fminf(fminf(Fc0, Fc1), fminf(Fc2, Fc3));
    const float maxF = fmaxf(fmaxf(Fc0, Fc1), fmaxf(Fc2, Fc3));
    const float minS = fminf(fminf(Sc0, Sc1), fminf(Sc2, Sc3));
    const float maxS = fmaxf(fmaxf(Sc0, Sc1), fmaxf(Sc2, Sc3));

    const int jlane = j0 + l;
    const bool jvalid = jlane < P;

    // dead tile: no lane can have F,S both in (0,513)
    const bool tile_live = (maxF > 0.0f) && (minF < 513.0f) &&
                           (maxS > 0.0f) && (minS < 513.0f);
    if (!tile_live) {
        for (int il = w; il < TI; il += 4) {
            const int i = i0 + il;
            if (i >= P) break;
            if (jvalid)
                __builtin_nontemporal_store(0.0f, rot + ((size_t)a * P + i) * P + jlane);
        }
        return;
    }

    int f0 = (int)floorf(minF) - 1;
    f0 = min(max(f0, 0), PSTRIDE - LDS_W) & ~3;     // 4-aligned, <=440
    int s0 = (int)floorf(minS) - 1;
    s0 = min(max(s0, 0), PROWS - LDS_ROWS);         // <=439

    // stage fixed 77x80 box: float4 loads/writes, fully coalesced, in-bounds
    {
        const float* src = bimg + (size_t)s0 * PSTRIDE + f0;
        for (int t = tid; t < STAGE_QUADS; t += 256) {
            const int r = t / 20;
            const int q = t - r * 20;
            const vfloat4 v = *(const vfloat4*)(src + r * PSTRIDE + (q << 2));
            *(vfloat4*)&lds[r * LDS_STRIDE + (q << 2)] = v;
        }
    }
    __syncthreads();

    const float jlf = (float)jlane;
    const float Fj = fmaf(FcJ, jlf, F0);
    const float Sj = fmaf(ScJ, jlf, S0);

    for (int il = w; il < TI; il += 4) {
        const int i = i0 + il;
        if (i >= P) break;
        const float fif = (float)i;
        const float F = fmaf(FcI, fif, Fj);
        const float S = fmaf(ScI, fif, Sj);
        const bool live = jvalid && (F > 0.0f) && (F < 513.0f)
                                 && (S > 0.0f) && (S < 513.0f);
        const float Ff = floorf(F), Sf = floorf(S);
        const float wf1 = F - Ff, ws1 = S - Sf;
        const float wf0 = 1.0f - wf1, ws0 = 1.0f - ws1;
        const int lx = min(max((int)Ff - f0, 0), LDS_W - 2);     // live lanes in-box
        const int ly = min(max((int)Sf - s0, 0), LDS_ROWS - 2);
        const float* bp = &lds[ly * LDS_STRIDE + lx];
        const float v00 = bp[0],          v01 = bp[1];           // ds_read2_b32
        const float v10 = bp[LDS_STRIDE], v11 = bp[LDS_STRIDE + 1];
        float v = fmaf(ws1, fmaf(wf1, v11, wf0 * v10),
                       ws0 * fmaf(wf1, v01, wf0 * v00));
        v = live ? v : 0.0f;
        if (jvalid)
            __builtin_nontemporal_store(v, rot + ((size_t)a * P + i) * P + jlane);
        float rsum = v;
        for (int off = 32; off > 0; off >>= 1)
            rsum += __shfl_down(rsum, off, 64);
        if (l == 0) atomicAdd(&sino[a * P + i], rsum);
    }
}

// ---------------- fallback (no workspace): direct bounds-checked gather ------
__global__ __launch_bounds__(256) void radon_fallback(
    const float* __restrict__ x, float* __restrict__ sino, float* __restrict__ rot)
{
    const int a = blockIdx.y, i = blockIdx.x, tid = threadIdx.x;
    const float deg = (float)a * (180.0f / 179.0f);
    const float ang = deg * (float)(M_PI / 180.0);
    const float c = cosf(ang), s = sinf(ang);
    const float fi = (float)i - 361.5f;
    const float Kx = 255.5f - 361.5f * c - s * fi;
    const float Ky = 255.5f - 361.5f * s + c * fi;
    float* rrow = rot + (size_t)(a * P + i) * P;
    float lsum = 0.0f;
    for (int j = tid; j < P; j += 256) {
        const float jf = (float)j;
        const float ix = fmaf(jf, c, Kx), iy = fmaf(jf, s, Ky);
        const float x0f = floorf(ix), y0f = floorf(iy);
        const int x0 = (int)x0f, y0 = (int)y0f;
        const int x1 = x0 + 1, y1 = y0 + 1;
        float wx1 = ix - x0f, wy1 = iy - y0f;
        float wx0 = 1.0f - wx1, wy0 = 1.0f - wy1;
        wx0 = ((unsigned)x0 < 512u) ? wx0 : 0.0f;
        wx1 = ((unsigned)x1 < 512u) ? wx1 : 0.0f;
        wy0 = ((unsigned)y0 < 512u) ? wy0 : 0.0f;
        wy1 = ((unsigned)y1 < 512u) ? wy1 : 0.0f;
        const int xa = min(max(x0, 0), 511), xb = min(max(x1, 0), 511);
        const int ya = min(max(y0, 0), 511), yb = min(max(y1, 0), 511);
        const float v00 = x[(ya << 9) + xa], v01 = x[(ya << 9) + xb];
        const float v10 = x[(yb << 9) + xa], v11 = x[(yb << 9) + xb];
        const float val = fmaf(wy1, fmaf(wx1, v11, wx0 * v10),
                               wy0 * fmaf(wx1, v01, wx0 * v00));
        __builtin_nontemporal_store(val, &rrow[j]);
        lsum += val;
    }
    for (int off = 32; off > 0; off >>= 1) lsum += __shfl_down(lsum, off, 64);
    __shared__ float ws_red[4];
    if ((tid & 63) == 0) ws_red[tid >> 6] = lsum;
    __syncthreads();
    if (tid == 0) sino[a * P + i] = ws_red[0] + ws_red[1] + ws_red[2] + ws_red[3];
}

// ---------------- launch ----------------
extern "C" void kernel_launch(void* const* d_in, const int* in_sizes, int n_in,
                              void* d_out, int out_size, void* d_ws, size_t ws_size,
                              hipStream_t stream) {
    const float* x = (const float*)d_in[0];
    float* sino = (float*)d_out;                       // [180*724]
    float* rot  = sino + (size_t)N_ANGLES * P;         // [180*724*724]
    float* ws   = (float*)d_ws;

    const size_t need = (size_t)(512 + 2 * IMGFLOATS + 128) * sizeof(float);

    if (ws && ws_size >= need) {
        float* img0 = ws + 512;
        float* imgT = img0 + IMGFLOATS;
        prep_pad<<<dim3(17, 65), dim3(256), 0, stream>>>(x, img0, imgT, (float2*)ws, sino);
        radon_tiled<<<dim3(TILES_J * TILES_I, N_ANGLES), dim3(256), 0, stream>>>(
            (const float2*)ws, img0, imgT, sino, rot);
    } else {
        radon_fallback<<<dim3(P, N_ANGLES), dim3(256), 0, stream>>>(x, sino, rot);
    }
}